// Round 2
// baseline (1527.067 us; speedup 1.0000x reference)
//
#include <hip/hip_runtime.h>
#include <math.h>

// Problem constants (from reference)
#define BDIM   16
#define CDIM   1024
#define TDIM   64
#define NDIM   12
#define NFRDIM 1024
#define BT_TOT 1024              // B*T
#define OUT_MAIN (12582912)      // BT*N*NFG_ONE = 1024*12*1024
#define MASK_TH 0.4f             // POS_THRESHOLD * OW = 0.005*80
#define LN_EPS 1e-5f

__device__ __forceinline__ float bf2f(unsigned short u) {
    return __uint_as_float(((unsigned int)u) << 16);
}
__device__ __forceinline__ unsigned short f2bf(float f) {
    unsigned int u = __float_as_uint(f);
    unsigned int r = (u + 0x7FFFu + ((u >> 16) & 1u)) >> 16;   // RNE
    return (unsigned short)r;
}

__global__ __launch_bounds__(256, 3)
void stgcn_frame_kernel(const float* __restrict__ x,   const float* __restrict__ A,
                        const float* __restrict__ wth, const float* __restrict__ bth,
                        const float* __restrict__ wph, const float* __restrict__ bph,
                        const float* __restrict__ wg,  const float* __restrict__ lnw,
                        const float* __restrict__ lnb, float* __restrict__ out)
{
    const int bt   = blockIdx.x;
    const int b    = bt >> 6;          // T = 64
    const int t    = bt & 63;
    const int tid  = threadIdx.x;
    const int lane = tid & 63;

    __shared__ unsigned short featS[NDIM][1024];   // feat, bf16
    __shared__ unsigned short thS[NDIM][1024];     // theta (scaled) bf16, later agg1 bf16
    __shared__ float cxS[NDIM], cyS[NDIM], sqS[NDIM];
    __shared__ float logitsS[NDIM][NDIM];
    __shared__ float relS[NDIM][NDIM];
    __shared__ float redS[2][256];

    // ---- phase 0: box centers + zero logits -------------------------------
    if (tid < NDIM) {
        const float4 box = *(const float4*)(A + ((size_t)bt * NDIM + tid) * 4);
        float cx = (box.x + box.z) * 0.5f;
        float cy = (box.y + box.w) * 0.5f;
        cxS[tid] = cx; cyS[tid] = cy; sqS[tid] = cx * cx + cy * cy;
    }
    if (tid < NDIM * NDIM) ((float*)logitsS)[tid] = 0.f;

    // ---- phase 1: load feat (transpose x[b,c,t,n] -> feat[n][c]) ----------
    #pragma unroll
    for (int j = 0; j < 4; ++j) {
        const int c = j * 256 + tid;
        const float* xp = x + ((size_t)((b * CDIM + c) * TDIM + t)) * NDIM;
        const float4 a0 = *(const float4*)(xp);
        const float4 a1 = *(const float4*)(xp + 4);
        const float4 a2 = *(const float4*)(xp + 8);
        featS[0][c]  = f2bf(a0.x); featS[1][c]  = f2bf(a0.y);
        featS[2][c]  = f2bf(a0.z); featS[3][c]  = f2bf(a0.w);
        featS[4][c]  = f2bf(a1.x); featS[5][c]  = f2bf(a1.y);
        featS[6][c]  = f2bf(a1.z); featS[7][c]  = f2bf(a1.w);
        featS[8][c]  = f2bf(a2.x); featS[9][c]  = f2bf(a2.y);
        featS[10][c] = f2bf(a2.z); featS[11][c] = f2bf(a2.w);
    }
    __syncthreads();

    // ---- phase 2: theta & phi GEMMs (thread owns r = tid + 256*j) ---------
    float accT[NDIM][4], accP[NDIM][4];
    {
        float btv[4], bpv[4];
        #pragma unroll
        for (int j = 0; j < 4; ++j) {
            btv[j] = bth[tid + 256 * j];
            bpv[j] = bph[tid + 256 * j];
        }
        #pragma unroll
        for (int n = 0; n < NDIM; ++n)
            #pragma unroll
            for (int j = 0; j < 4; ++j) { accT[n][j] = btv[j]; accP[n][j] = bpv[j]; }
    }
    for (int c = 0; c < 1024; ++c) {
        float f[NDIM];
        #pragma unroll
        for (int n = 0; n < NDIM; ++n) f[n] = bf2f(featS[n][c]);
        const float* wtr = wth + (size_t)c * NFRDIM;
        const float* wpr = wph + (size_t)c * NFRDIM;
        float wt[4], wp[4];
        #pragma unroll
        for (int j = 0; j < 4; ++j) { wt[j] = wtr[tid + 256 * j]; wp[j] = wpr[tid + 256 * j]; }
        #pragma unroll
        for (int n = 0; n < NDIM; ++n)
            #pragma unroll
            for (int j = 0; j < 4; ++j) {
                accT[n][j] = fmaf(f[n], wt[j], accT[n][j]);
                accP[n][j] = fmaf(f[n], wp[j], accP[n][j]);
            }
    }
    // stash theta (folding the 1/sqrt(1024) logits scale) as bf16
    {
        const float sc = 0.03125f;
        #pragma unroll
        for (int n = 0; n < NDIM; ++n)
            #pragma unroll
            for (int j = 0; j < 4; ++j)
                thS[n][tid + 256 * j] = f2bf(accT[n][j] * sc);
    }
    __syncthreads();

    // ---- phase 3: logits[n][m] = sum_r theta_s[n][r] * phi[m][r] ----------
    for (int n = 0; n < NDIM; ++n) {
        float th[4];
        #pragma unroll
        for (int j = 0; j < 4; ++j) th[j] = bf2f(thS[n][tid + 256 * j]);
        float p[NDIM];
        #pragma unroll
        for (int m = 0; m < NDIM; ++m) {
            p[m] = th[0] * accP[m][0] + th[1] * accP[m][1]
                 + th[2] * accP[m][2] + th[3] * accP[m][3];
        }
        #pragma unroll
        for (int m = 0; m < NDIM; ++m) {
            #pragma unroll
            for (int msk = 32; msk >= 1; msk >>= 1)
                p[m] += __shfl_xor(p[m], msk, 64);
        }
        if (lane == 0) {
            #pragma unroll
            for (int m = 0; m < NDIM; ++m) atomicAdd(&logitsS[n][m], p[m]);
        }
    }
    __syncthreads();

    // ---- phase 4: mask + row softmax (threads 0..11), write relation out --
    if (tid < NDIM) {
        const int n = tid;
        float l[NDIM];
        float mx = -3.4e38f;
        #pragma unroll
        for (int m = 0; m < NDIM; ++m) {
            float d2 = sqS[n] - 2.f * (cxS[n] * cxS[m] + cyS[n] * cyS[m]) + sqS[m];
            float dist = sqrtf(fmaxf(d2, 0.f));
            float v = logitsS[n][m];
            if (dist > MASK_TH) v = -INFINITY;
            l[m] = v;
            mx = fmaxf(mx, v);
        }
        float s = 0.f, e[NDIM];
        #pragma unroll
        for (int m = 0; m < NDIM; ++m) { e[m] = expf(l[m] - mx); s += e[m]; }
        const float inv = 1.f / s;
        float* orel = out + (size_t)OUT_MAIN + (size_t)bt * (NDIM * NDIM) + n * NDIM;
        #pragma unroll
        for (int m = 0; m < NDIM; ++m) {
            float r = e[m] * inv;
            relS[n][m] = r;
            orel[m] = r;
        }
    }
    __syncthreads();

    // ---- phase 5: agg1 = rel @ feat  -> thS (bf16, overwrite theta) -------
    #pragma unroll
    for (int j = 0; j < 4; ++j) {
        const int c = j * 256 + tid;
        float f[NDIM];
        #pragma unroll
        for (int m = 0; m < NDIM; ++m) f[m] = bf2f(featS[m][c]);
        #pragma unroll
        for (int n = 0; n < NDIM; ++n) {
            float s = 0.f;
            #pragma unroll
            for (int m = 0; m < NDIM; ++m) s = fmaf(relS[n][m], f[m], s);
            thS[n][c] = f2bf(s);
        }
    }
    __syncthreads();

    // ---- phase 6: agg2 = agg1 @ w_gcn -------------------------------------
    float acc2[NDIM][4];
    #pragma unroll
    for (int n = 0; n < NDIM; ++n)
        #pragma unroll
        for (int j = 0; j < 4; ++j) acc2[n][j] = 0.f;
    for (int c = 0; c < 1024; ++c) {
        float g[NDIM];
        #pragma unroll
        for (int n = 0; n < NDIM; ++n) g[n] = bf2f(thS[n][c]);
        const float* wgr = wg + (size_t)c * NFRDIM;
        float w4[4];
        #pragma unroll
        for (int j = 0; j < 4; ++j) w4[j] = wgr[tid + 256 * j];
        #pragma unroll
        for (int n = 0; n < NDIM; ++n)
            #pragma unroll
            for (int j = 0; j < 4; ++j) acc2[n][j] = fmaf(g[n], w4[j], acc2[n][j]);
    }

    // ---- phase 7: LayerNorm over all 12*1024 values of this frame ---------
    float s = 0.f, s2 = 0.f;
    #pragma unroll
    for (int n = 0; n < NDIM; ++n)
        #pragma unroll
        for (int j = 0; j < 4; ++j) { float v = acc2[n][j]; s += v; s2 += v * v; }
    redS[0][tid] = s; redS[1][tid] = s2;
    __syncthreads();
    for (int o = 128; o > 0; o >>= 1) {
        if (tid < o) {
            redS[0][tid] += redS[0][tid + o];
            redS[1][tid] += redS[1][tid + o];
        }
        __syncthreads();
    }
    const float mu   = redS[0][0] * (1.f / 12288.f);
    const float var  = redS[1][0] * (1.f / 12288.f) - mu * mu;
    const float rstd = rsqrtf(var + LN_EPS);
    float* oo = out + (size_t)bt * (NDIM * NFRDIM);
    #pragma unroll
    for (int n = 0; n < NDIM; ++n)
        #pragma unroll
        for (int j = 0; j < 4; ++j) {
            const int r = tid + 256 * j;
            float v = (acc2[n][j] - mu) * rstd;
            v = fmaf(v, lnw[n * NFRDIM + r], lnb[n * NFRDIM + r]);
            oo[n * NFRDIM + r] = fmaxf(v, 0.f);
        }
}

extern "C" void kernel_launch(void* const* d_in, const int* in_sizes, int n_in,
                              void* d_out, int out_size, void* d_ws, size_t ws_size,
                              hipStream_t stream) {
    const float* x   = (const float*)d_in[0];
    const float* A   = (const float*)d_in[1];
    const float* wth = (const float*)d_in[2];
    const float* bth = (const float*)d_in[3];
    const float* wph = (const float*)d_in[4];
    const float* bph = (const float*)d_in[5];
    const float* wg  = (const float*)d_in[6];
    const float* lnw = (const float*)d_in[7];
    const float* lnb = (const float*)d_in[8];
    float* out = (float*)d_out;

    stgcn_frame_kernel<<<BT_TOT, 256, 0, stream>>>(x, A, wth, bth, wph, bph,
                                                   wg, lnw, lnb, out);
}

// Round 3
// 368.828 us; speedup vs baseline: 4.1403x; 4.1403x over previous
//
#include <hip/hip_runtime.h>
#include <math.h>
#include <stdint.h>

#define NDIM   12
#define KDIM   1024
#define BT_TOT 1024
#define M_TOT  (BT_TOT * NDIM)       // 12288
#define OUT_MAIN (M_TOT * KDIM)      // 12582912
#define MASK_TH 0.4f                 // 0.005 * 80
#define LN_EPS 1e-5f

typedef float f32x4 __attribute__((ext_vector_type(4)));
typedef short bf16x8 __attribute__((ext_vector_type(8)));

__device__ __forceinline__ float bf2f(unsigned short u) {
    return __uint_as_float(((unsigned int)u) << 16);
}
__device__ __forceinline__ unsigned short f2bf(float f) {
    unsigned int u = __float_as_uint(f);
    return (unsigned short)((u + 0x7FFFu + ((u >> 16) & 1u)) >> 16);   // RNE
}
__device__ __forceinline__ void gld16(const void* g, void* l) {
    __builtin_amdgcn_global_load_lds(
        (const __attribute__((address_space(1))) unsigned int*)g,
        (__attribute__((address_space(3))) unsigned int*)l, 16, 0, 0);
}

// ---- K0: weights [c][o] fp32 -> [o][c] bf16 --------------------------------
__global__ __launch_bounds__(256)
void transw_kernel(const float* __restrict__ w0, const float* __restrict__ w1,
                   const float* __restrict__ w2, unsigned short* __restrict__ t0,
                   unsigned short* __restrict__ t1, unsigned short* __restrict__ t2)
{
    const float* src = blockIdx.z == 0 ? w0 : (blockIdx.z == 1 ? w1 : w2);
    unsigned short* dst = blockIdx.z == 0 ? t0 : (blockIdx.z == 1 ? t1 : t2);
    __shared__ float tile[32][33];
    const int c0 = blockIdx.y * 32, o0 = blockIdx.x * 32;
    const int tx = threadIdx.x & 31, ty = threadIdx.x >> 5;
    #pragma unroll
    for (int i = 0; i < 4; ++i) {
        int r = ty + i * 8;
        tile[r][tx] = src[(size_t)(c0 + r) * KDIM + o0 + tx];
    }
    __syncthreads();
    #pragma unroll
    for (int i = 0; i < 4; ++i) {
        int r = ty + i * 8;
        dst[(size_t)(o0 + r) * KDIM + c0 + tx] = f2bf(tile[tx][r]);
    }
}

// ---- K1: x [B,C,T,N] fp32 -> featB [BT*N][C] bf16 --------------------------
__global__ __launch_bounds__(256)
void feat_kernel(const float* __restrict__ x, unsigned short* __restrict__ featB)
{
    const int bt = blockIdx.x, b = bt >> 6, t = bt & 63, tid = threadIdx.x;
    #pragma unroll
    for (int j = 0; j < 4; ++j) {
        const int c = j * 256 + tid;
        const float* xp = x + ((size_t)(b * KDIM + c) * 64 + t) * NDIM;
        const float4 a0 = *(const float4*)(xp);
        const float4 a1 = *(const float4*)(xp + 4);
        const float4 a2 = *(const float4*)(xp + 8);
        float v[12] = {a0.x, a0.y, a0.z, a0.w, a1.x, a1.y, a1.z, a1.w,
                       a2.x, a2.y, a2.z, a2.w};
        #pragma unroll
        for (int n = 0; n < NDIM; ++n)
            featB[(size_t)(bt * NDIM + n) * KDIM + c] = f2bf(v[n]);
    }
}

// ---- K2/K5: C[M,1024] = A[M,1024] @ B^T (B stored [o][c]) , bf16 MFMA ------
template<bool BIAS>
__global__ __launch_bounds__(256)
void gemm_kernel(const unsigned short* __restrict__ A,
                 const unsigned short* __restrict__ B0, const unsigned short* __restrict__ B1,
                 const float* __restrict__ bias0, const float* __restrict__ bias1,
                 unsigned short* __restrict__ C0, unsigned short* __restrict__ C1)
{
    const unsigned short* B = blockIdx.z ? B1 : B0;
    const float* bias       = blockIdx.z ? bias1 : bias0;
    unsigned short* C       = blockIdx.z ? C1 : C0;

    const int tid = threadIdx.x, lane = tid & 63, wid = tid >> 6;
    const int m0 = blockIdx.y * 128, n0 = blockIdx.x * 128;
    const int wr = wid >> 1, wc = wid & 1;

    __shared__ __align__(16) unsigned short As[128 * 32];
    __shared__ __align__(16) unsigned short Bs[128 * 32];

    f32x4 acc[4][4] = {};

    const int srow = tid >> 2;          // staging row (issue 0)
    const int scol = (tid & 3) * 16;    // byte within 64B row

    for (int k0 = 0; k0 < KDIM; k0 += 32) {
        const char* gA = (const char*)A + ((size_t)(m0 + srow) * KDIM + k0) * 2 + scol;
        const char* gB = (const char*)B + ((size_t)(n0 + srow) * KDIM + k0) * 2 + scol;
        char* lA = (char*)As + wid * 1024;
        char* lB = (char*)Bs + wid * 1024;
        gld16(gA, lA);
        gld16(gA + (size_t)64 * KDIM * 2, lA + 4096);
        gld16(gB, lB);
        gld16(gB + (size_t)64 * KDIM * 2, lB + 4096);
        __syncthreads();

        bf16x8 af[4], bfr[4];
        const int rA = wr * 64 + (lane & 15);
        const int rB = wc * 64 + (lane & 15);
        const int kq = (lane >> 4) * 8;
        #pragma unroll
        for (int mi = 0; mi < 4; ++mi)
            af[mi] = *(const bf16x8*)&As[(rA + mi * 16) * 32 + kq];
        #pragma unroll
        for (int ni = 0; ni < 4; ++ni)
            bfr[ni] = *(const bf16x8*)&Bs[(rB + ni * 16) * 32 + kq];
        #pragma unroll
        for (int mi = 0; mi < 4; ++mi)
            #pragma unroll
            for (int ni = 0; ni < 4; ++ni)
                acc[mi][ni] = __builtin_amdgcn_mfma_f32_16x16x32_bf16(
                    af[mi], bfr[ni], acc[mi][ni], 0, 0, 0);
        __syncthreads();
    }

    // epilogue: C/D layout col=lane&15, row=(lane>>4)*4+reg  [m89/m91]
    #pragma unroll
    for (int mi = 0; mi < 4; ++mi) {
        const int gr0 = m0 + wr * 64 + mi * 16 + (lane >> 4) * 4;
        #pragma unroll
        for (int ni = 0; ni < 4; ++ni) {
            const int gc = n0 + wc * 64 + ni * 16 + (lane & 15);
            float bv = 0.f;
            if (BIAS) bv = bias[gc];
            const f32x4 v = acc[mi][ni];
            #pragma unroll
            for (int reg = 0; reg < 4; ++reg)
                C[(size_t)(gr0 + reg) * KDIM + gc] = f2bf(v[reg] + bv);
        }
    }
}

// ---- K3: per-frame logits + mask + softmax + agg1 --------------------------
#define THP 1048   // padded row stride (bf16 elems): byte stride 2096 (16B mult)
__global__ __launch_bounds__(256)
void rel_kernel(const unsigned short* __restrict__ thetaB,
                const unsigned short* __restrict__ phiB,
                const unsigned short* __restrict__ featB,
                const float* __restrict__ Abox,
                float* __restrict__ out, unsigned short* __restrict__ agg1B)
{
    const int f = blockIdx.x, tid = threadIdx.x;
    __shared__ __align__(16) unsigned short thS[NDIM * THP];
    __shared__ __align__(16) unsigned short phS[NDIM * THP];
    __shared__ float cxS[NDIM], cyS[NDIM], sqS[NDIM];
    __shared__ float logitS[144], relS[144];

    if (tid < NDIM) {
        const float4 box = *(const float4*)(Abox + ((size_t)f * NDIM + tid) * 4);
        const float cx = (box.x + box.z) * 0.5f, cy = (box.y + box.w) * 0.5f;
        cxS[tid] = cx; cyS[tid] = cy; sqS[tid] = cx * cx + cy * cy;
    }
    const uint4* gth = (const uint4*)(thetaB + (size_t)f * NDIM * KDIM);
    const uint4* gph = (const uint4*)(phiB   + (size_t)f * NDIM * KDIM);
    #pragma unroll
    for (int i = 0; i < 6; ++i) {
        const int e = (i * 256 + tid) * 8, row = e >> 10, col = e & 1023;
        *(uint4*)&thS[row * THP + col] = gth[i * 256 + tid];
        *(uint4*)&phS[row * THP + col] = gph[i * 256 + tid];
    }
    __syncthreads();

    if (tid < 144) {
        const int n = tid / 12, m = tid % 12;
        const unsigned short* tr = &thS[n * THP];
        const unsigned short* pr = &phS[m * THP];
        float acc = 0.f;
        for (int i = 0; i < 128; ++i) {
            const bf16x8 a = *(const bf16x8*)&tr[i * 8];
            const bf16x8 b = *(const bf16x8*)&pr[i * 8];
            #pragma unroll
            for (int j = 0; j < 8; ++j)
                acc = fmaf(bf2f((unsigned short)a[j]), bf2f((unsigned short)b[j]), acc);
        }
        logitS[tid] = acc * 0.03125f;   // 1/sqrt(1024)
    }
    __syncthreads();

    if (tid < NDIM) {
        const int n = tid;
        float l[NDIM], mx = -3.4e38f;
        #pragma unroll
        for (int m = 0; m < NDIM; ++m) {
            const float d2 = sqS[n] - 2.f * (cxS[n] * cxS[m] + cyS[n] * cyS[m]) + sqS[m];
            const float dist = sqrtf(fmaxf(d2, 0.f));
            float v = logitS[n * 12 + m];
            if (dist > MASK_TH) v = -INFINITY;
            l[m] = v; mx = fmaxf(mx, v);
        }
        float s = 0.f, e[NDIM];
        #pragma unroll
        for (int m = 0; m < NDIM; ++m) { e[m] = expf(l[m] - mx); s += e[m]; }
        const float inv = 1.f / s;
        float* orel = out + (size_t)OUT_MAIN + (size_t)f * 144 + n * 12;
        #pragma unroll
        for (int m = 0; m < NDIM; ++m) {
            const float r = e[m] * inv;
            relS[n * 12 + m] = r;
            orel[m] = r;
        }
    }
    __syncthreads();

    #pragma unroll
    for (int j = 0; j < 4; ++j) {
        const int c = j * 256 + tid;
        float fm[NDIM];
        #pragma unroll
        for (int m = 0; m < NDIM; ++m)
            fm[m] = bf2f(featB[(size_t)(f * NDIM + m) * KDIM + c]);
        #pragma unroll
        for (int n = 0; n < NDIM; ++n) {
            float s = 0.f;
            #pragma unroll
            for (int m = 0; m < NDIM; ++m) s = fmaf(relS[n * 12 + m], fm[m], s);
            agg1B[(size_t)(f * NDIM + n) * KDIM + c] = f2bf(s);
        }
    }
}

// ---- K6: per-frame mean/rstd over agg2 -------------------------------------
__global__ __launch_bounds__(256)
void stats_kernel(const unsigned short* __restrict__ agg2B, float* __restrict__ stats)
{
    const int f = blockIdx.x, tid = threadIdx.x;
    const uint4* g = (const uint4*)(agg2B + (size_t)f * 12288);
    float s = 0.f, s2 = 0.f;
    #pragma unroll
    for (int i = 0; i < 6; ++i) {
        uint4 v = g[i * 256 + tid];
        const unsigned short* p = (const unsigned short*)&v;
        #pragma unroll
        for (int j = 0; j < 8; ++j) { const float x = bf2f(p[j]); s += x; s2 += x * x; }
    }
    __shared__ float rs[2][256];
    rs[0][tid] = s; rs[1][tid] = s2;
    __syncthreads();
    for (int o = 128; o > 0; o >>= 1) {
        if (tid < o) { rs[0][tid] += rs[0][tid + o]; rs[1][tid] += rs[1][tid + o]; }
        __syncthreads();
    }
    if (tid == 0) {
        const float mu = rs[0][0] * (1.f / 12288.f);
        const float var = rs[1][0] * (1.f / 12288.f) - mu * mu;
        stats[f * 2] = mu;
        stats[f * 2 + 1] = rsqrtf(var + LN_EPS);
    }
}

// ---- K7: LayerNorm + ReLU --------------------------------------------------
__global__ __launch_bounds__(256)
void ln_kernel(const unsigned short* __restrict__ agg2B, const float* __restrict__ stats,
               const float* __restrict__ lnw, const float* __restrict__ lnb,
               float* __restrict__ out)
{
    const size_t idx = (size_t)blockIdx.x * 256 + threadIdx.x;
    const size_t e0 = idx * 8;
    const int row = (int)(e0 >> 10), c = (int)(e0 & 1023);
    const int f = row / 12, n = row - f * 12;
    const float mu = stats[f * 2], rstd = stats[f * 2 + 1];
    uint4 v = *(const uint4*)(agg2B + e0);
    const unsigned short* p = (const unsigned short*)&v;
    const float* w = lnw + (size_t)n * KDIM + c;
    const float* b = lnb + (size_t)n * KDIM + c;
    const float4 w0 = *(const float4*)w,       w1 = *(const float4*)(w + 4);
    const float4 b0 = *(const float4*)b,       b1 = *(const float4*)(b + 4);
    float o[8];
    const float ww[8] = {w0.x, w0.y, w0.z, w0.w, w1.x, w1.y, w1.z, w1.w};
    const float bb[8] = {b0.x, b0.y, b0.z, b0.w, b1.x, b1.y, b1.z, b1.w};
    #pragma unroll
    for (int j = 0; j < 8; ++j)
        o[j] = fmaxf(fmaf((bf2f(p[j]) - mu) * rstd, ww[j], bb[j]), 0.f);
    *(float4*)(out + e0)     = make_float4(o[0], o[1], o[2], o[3]);
    *(float4*)(out + e0 + 4) = make_float4(o[4], o[5], o[6], o[7]);
}

extern "C" void kernel_launch(void* const* d_in, const int* in_sizes, int n_in,
                              void* d_out, int out_size, void* d_ws, size_t ws_size,
                              hipStream_t stream) {
    const float* x   = (const float*)d_in[0];
    const float* A   = (const float*)d_in[1];
    const float* wth = (const float*)d_in[2];
    const float* bth = (const float*)d_in[3];
    const float* wph = (const float*)d_in[4];
    const float* bph = (const float*)d_in[5];
    const float* wg  = (const float*)d_in[6];
    const float* lnw = (const float*)d_in[7];
    const float* lnb = (const float*)d_in[8];
    float* out = (float*)d_out;

    char* ws = (char*)d_ws;
    const size_t WSZ = (size_t)1024 * 1024;
    unsigned short* wthT  = (unsigned short*)(ws);                    // 2 MB
    unsigned short* wphT  = (unsigned short*)(ws + 2 * WSZ);          // 2 MB
    unsigned short* wgT   = (unsigned short*)(ws + 4 * WSZ);          // 2 MB
    unsigned short* featB = (unsigned short*)(ws + 6 * WSZ);          // 24 MB
    unsigned short* thetaB = (unsigned short*)(ws + 30 * WSZ);        // 24 MB
    unsigned short* phiB   = (unsigned short*)(ws + 54 * WSZ);        // 24 MB
    float* stats = (float*)(ws + 78 * WSZ);                           // 8 KB
    unsigned short* agg1B = thetaB;   // alias: rel_kernel rewrites its own rows
    unsigned short* agg2B = phiB;     // alias: phi dead after rel_kernel

    transw_kernel<<<dim3(32, 32, 3), 256, 0, stream>>>(wth, wph, wg, wthT, wphT, wgT);
    feat_kernel<<<BT_TOT, 256, 0, stream>>>(x, featB);
    gemm_kernel<true><<<dim3(8, 96, 2), 256, 0, stream>>>(
        featB, wthT, wphT, bth, bph, thetaB, phiB);
    rel_kernel<<<BT_TOT, 256, 0, stream>>>(thetaB, phiB, featB, A, out, agg1B);
    gemm_kernel<false><<<dim3(8, 96, 1), 256, 0, stream>>>(
        agg1B, wgT, wgT, nullptr, nullptr, agg2B, agg2B);
    stats_kernel<<<BT_TOT, 256, 0, stream>>>(agg2B, stats);
    ln_kernel<<<M_TOT * KDIM / 2048, 256, 0, stream>>>(agg2B, stats, lnw, lnb, out);
}

// Round 6
// 299.196 us; speedup vs baseline: 5.1039x; 1.2327x over previous
//
#include <hip/hip_runtime.h>
#include <math.h>
#include <stdint.h>

#define NDIM   12
#define KDIM   1024
#define BT_TOT 1024
#define M_TOT  (BT_TOT * NDIM)       // 12288
#define OUT_MAIN (M_TOT * KDIM)      // 12582912
#define MASK_TH 0.4f                 // 0.005 * 80
#define LN_EPS 1e-5f

typedef float f32x4 __attribute__((ext_vector_type(4)));
typedef short bf16x8 __attribute__((ext_vector_type(8)));
typedef short bf16x4 __attribute__((ext_vector_type(4)));

__device__ __forceinline__ float bf2f(unsigned short u) {
    return __uint_as_float(((unsigned int)u) << 16);
}
__device__ __forceinline__ unsigned short f2bf(float f) {
    unsigned int u = __float_as_uint(f);
    return (unsigned short)((u + 0x7FFFu + ((u >> 16) & 1u)) >> 16);   // RNE
}
__device__ __forceinline__ void gld16(const void* g, void* l) {
    __builtin_amdgcn_global_load_lds(
        (const __attribute__((address_space(1))) unsigned int*)g,
        (__attribute__((address_space(3))) unsigned int*)l, 16, 0, 0);
}

// ---- K0a: wth, wph fp32 -> bf16 (same layout [in][out]) --------------------
__global__ __launch_bounds__(256)
void castw_kernel(const float* __restrict__ wth, const float* __restrict__ wph,
                  unsigned short* __restrict__ t0, unsigned short* __restrict__ t1)
{
    const int bid = blockIdx.x;
    const float* src = bid < 512 ? wth : wph;
    unsigned short* dst = bid < 512 ? t0 : t1;
    const size_t off = (size_t)(bid & 511) * 2048 + (size_t)threadIdx.x * 8;
    const float4 a = *(const float4*)(src + off);
    const float4 b = *(const float4*)(src + off + 4);
    unsigned short o[8] = {f2bf(a.x), f2bf(a.y), f2bf(a.z), f2bf(a.w),
                           f2bf(b.x), f2bf(b.y), f2bf(b.z), f2bf(b.w)};
    *(uint4*)(dst + off) = *(const uint4*)o;
}

// ---- K0b: wg [c][o] fp32 -> wgT [o][c] bf16 --------------------------------
__global__ __launch_bounds__(256)
void transwg_kernel(const float* __restrict__ w, unsigned short* __restrict__ dst)
{
    __shared__ float tile[32][33];
    const int c0 = blockIdx.y * 32, o0 = blockIdx.x * 32;
    const int tx = threadIdx.x & 31, ty = threadIdx.x >> 5;
    #pragma unroll
    for (int i = 0; i < 4; ++i) {
        const int r = ty + i * 8;
        tile[r][tx] = w[(size_t)(c0 + r) * KDIM + o0 + tx];
    }
    __syncthreads();
    #pragma unroll
    for (int i = 0; i < 4; ++i) {
        const int r = ty + i * 8;
        dst[(size_t)(o0 + r) * KDIM + c0 + tx] = f2bf(tile[tx][r]);
    }
}

// ---- K1: x [B,C,T,N] fp32 -> featB [BT*N][C] bf16 --------------------------
__global__ __launch_bounds__(256)
void feat_kernel(const float* __restrict__ x, unsigned short* __restrict__ featB)
{
    const int bt = blockIdx.x, b = bt >> 6, t = bt & 63, tid = threadIdx.x;
    #pragma unroll
    for (int j = 0; j < 4; ++j) {
        const int c = j * 256 + tid;
        const float* xp = x + ((size_t)(b * KDIM + c) * 64 + t) * NDIM;
        const float4 a0 = *(const float4*)(xp);
        const float4 a1 = *(const float4*)(xp + 4);
        const float4 a2 = *(const float4*)(xp + 8);
        float v[12] = {a0.x, a0.y, a0.z, a0.w, a1.x, a1.y, a1.z, a1.w,
                       a2.x, a2.y, a2.z, a2.w};
        #pragma unroll
        for (int n = 0; n < NDIM; ++n)
            featB[(size_t)(bt * NDIM + n) * KDIM + c] = f2bf(v[n]);
    }
}

// ---- K2: v = wph @ b_theta (fp32 matvec) -----------------------------------
__global__ __launch_bounds__(256)
void biasv_kernel(const float* __restrict__ wph, const float* __restrict__ btheta,
                  float* __restrict__ v)
{
    const int j = blockIdx.x * 256 + threadIdx.x;   // grid 4 -> 1024 rows
    const float4* row = (const float4*)(wph + (size_t)j * KDIM);
    const float4* bt4 = (const float4*)btheta;
    float s = 0.f;
    for (int i = 0; i < 256; ++i) {
        const float4 a = row[i], b = bt4[i];
        s += a.x * b.x + a.y * b.y + a.z * b.z + a.w * b.w;
    }
    v[j] = s;
}

// ---- K3: q[r] = featB[r] . v  (softmax column-bias term) -------------------
__global__ __launch_bounds__(256)
void qk_kernel(const unsigned short* __restrict__ featB, const float* __restrict__ v,
               float* __restrict__ q)
{
    __shared__ float vS[KDIM];
    const int tid = threadIdx.x;
    #pragma unroll
    for (int i = 0; i < 4; ++i) vS[tid + i * 256] = v[tid + i * 256];
    __syncthreads();
    const int r = blockIdx.x * 256 + tid;           // grid 48 -> 12288 rows
    const unsigned short* row = featB + (size_t)r * KDIM;
    float s = 0.f;
    for (int i = 0; i < 128; ++i) {
        const bf16x8 a = *(const bf16x8*)&row[i * 8];
        #pragma unroll
        for (int j = 0; j < 8; ++j)
            s = fmaf(bf2f((unsigned short)a[j]), vS[i * 8 + j], s);
    }
    q[r] = s;
}

// ---- K4/K5: C[M,1024] = A[M,1024] @ B^T, bf16 MFMA (verified R3) -----------
template<bool BIAS>
__global__ __launch_bounds__(256)
void gemm_kernel(const unsigned short* __restrict__ A,
                 const unsigned short* __restrict__ B0, const unsigned short* __restrict__ B1,
                 const float* __restrict__ bias0, const float* __restrict__ bias1,
                 unsigned short* __restrict__ C0, unsigned short* __restrict__ C1)
{
    const unsigned short* B = blockIdx.z ? B1 : B0;
    const float* bias       = blockIdx.z ? bias1 : bias0;
    unsigned short* C       = blockIdx.z ? C1 : C0;

    const int tid = threadIdx.x, lane = tid & 63, wid = tid >> 6;
    const int m0 = blockIdx.y * 128, n0 = blockIdx.x * 128;
    const int wr = wid >> 1, wc = wid & 1;

    __shared__ __align__(16) unsigned short As[128 * 32];
    __shared__ __align__(16) unsigned short Bs[128 * 32];

    f32x4 acc[4][4] = {};

    const int srow = tid >> 2;
    const int scol = (tid & 3) * 16;

    for (int k0 = 0; k0 < KDIM; k0 += 32) {
        const char* gA = (const char*)A + ((size_t)(m0 + srow) * KDIM + k0) * 2 + scol;
        const char* gB = (const char*)B + ((size_t)(n0 + srow) * KDIM + k0) * 2 + scol;
        char* lA = (char*)As + wid * 1024;
        char* lB = (char*)Bs + wid * 1024;
        gld16(gA, lA);
        gld16(gA + (size_t)64 * KDIM * 2, lA + 4096);
        gld16(gB, lB);
        gld16(gB + (size_t)64 * KDIM * 2, lB + 4096);
        __syncthreads();

        bf16x8 af[4], bfr[4];
        const int rA = wr * 64 + (lane & 15);
        const int rB = wc * 64 + (lane & 15);
        const int kq = (lane >> 4) * 8;
        #pragma unroll
        for (int mi = 0; mi < 4; ++mi)
            af[mi] = *(const bf16x8*)&As[(rA + mi * 16) * 32 + kq];
        #pragma unroll
        for (int ni = 0; ni < 4; ++ni)
            bfr[ni] = *(const bf16x8*)&Bs[(rB + ni * 16) * 32 + kq];
        #pragma unroll
        for (int mi = 0; mi < 4; ++mi)
            #pragma unroll
            for (int ni = 0; ni < 4; ++ni)
                acc[mi][ni] = __builtin_amdgcn_mfma_f32_16x16x32_bf16(
                    af[mi], bfr[ni], acc[mi][ni], 0, 0, 0);
        __syncthreads();
    }

    #pragma unroll
    for (int mi = 0; mi < 4; ++mi) {
        const int gr0 = m0 + wr * 64 + mi * 16 + (lane >> 4) * 4;
        #pragma unroll
        for (int ni = 0; ni < 4; ++ni) {
            const int gc = n0 + wc * 64 + ni * 16 + (lane & 15);
            float bv = 0.f;
            if (BIAS) bv = bias[gc];
            const f32x4 v = acc[mi][ni];
            #pragma unroll
            for (int reg = 0; reg < 4; ++reg)
                C[(size_t)(gr0 + reg) * KDIM + gc] = f2bf(v[reg] + bv);
        }
    }
}

// ---- K6: fused logits(MFMA) + mask/softmax + agg2 = rel@H + LN + ReLU ------
__global__ __launch_bounds__(256)
void relf_kernel(const unsigned short* __restrict__ G,
                 const unsigned short* __restrict__ featB,
                 const unsigned short* __restrict__ H,
                 const float* __restrict__ Abox, const float* __restrict__ q,
                 const float* __restrict__ lnw, const float* __restrict__ lnb,
                 float* __restrict__ out)
{
    const int f = blockIdx.x, tid = threadIdx.x, lane = tid & 63, w = tid >> 6;
    __shared__ float Lred[4][16][16];
    __shared__ float relS[12][12];
    __shared__ float cxS[12], cyS[12], sqS[12], qS[12];
    __shared__ float rs[2][256];

    if (tid < 12) {
        const float4 box = *(const float4*)(Abox + ((size_t)f * 12 + tid) * 4);
        const float cx = (box.x + box.z) * 0.5f, cy = (box.y + box.w) * 0.5f;
        cxS[tid] = cx; cyS[tid] = cy; sqS[tid] = cx * cx + cy * cy;
        qS[tid] = q[f * 12 + tid];
    }

    // logits = G . feat^T via MFMA; pad rows 12..15 with row 0 (their output
    // rows/cols are discarded — A row r only affects D row r, B col c only D col c)
    const int r = lane & 15, rr = r < 12 ? r : 0;
    const int kq = (lane >> 4) * 8;
    const unsigned short* gG = G + (size_t)(f * 12 + rr) * KDIM;
    const unsigned short* gF = featB + (size_t)(f * 12 + rr) * KDIM;
    f32x4 acc = {};
    #pragma unroll
    for (int s8 = 0; s8 < 8; ++s8) {
        const int k0 = (w * 8 + s8) * 32 + kq;
        const bf16x8 a = *(const bf16x8*)(gG + k0);
        const bf16x8 b = *(const bf16x8*)(gF + k0);
        acc = __builtin_amdgcn_mfma_f32_16x16x32_bf16(a, b, acc, 0, 0, 0);
    }
    {
        const int row0 = (lane >> 4) * 4, col = lane & 15;
        #pragma unroll
        for (int reg = 0; reg < 4; ++reg) Lred[w][row0 + reg][col] = acc[reg];
    }
    __syncthreads();

    if (tid < 12) {
        const int n = tid;
        float l[12], mx = -3.4e38f;
        #pragma unroll
        for (int m = 0; m < 12; ++m) {
            const float L = Lred[0][n][m] + Lred[1][n][m] + Lred[2][n][m] + Lred[3][n][m];
            float val = (L + qS[m]) * 0.03125f;    // 1/sqrt(1024); row-bias+const cancel in softmax
            const float d2 = sqS[n] - 2.f * (cxS[n] * cxS[m] + cyS[n] * cyS[m]) + sqS[m];
            const float dist = sqrtf(fmaxf(d2, 0.f));
            if (dist > MASK_TH) val = -INFINITY;
            l[m] = val; mx = fmaxf(mx, val);
        }
        float s = 0.f, e[12];
        #pragma unroll
        for (int m = 0; m < 12; ++m) { e[m] = expf(l[m] - mx); s += e[m]; }
        const float inv = 1.f / s;
        float* orel = out + (size_t)OUT_MAIN + (size_t)f * 144 + n * 12;
        #pragma unroll
        for (int m = 0; m < 12; ++m) {
            const float rv = e[m] * inv;
            relS[n][m] = rv;
            orel[m] = rv;
        }
    }
    __syncthreads();

    // agg2[n][c] = sum_m rel[n][m] * H[m][c];  thread owns c = tid*4 .. tid*4+3
    const int c0 = tid * 4;
    float h[12][4];
    #pragma unroll
    for (int m = 0; m < 12; ++m) {
        const bf16x4 h4 = *(const bf16x4*)(H + (size_t)(f * 12 + m) * KDIM + c0);
        #pragma unroll
        for (int j = 0; j < 4; ++j) h[m][j] = bf2f((unsigned short)h4[j]);
    }
    float a2[12][4];
    float s = 0.f, s2 = 0.f;
    #pragma unroll
    for (int n = 0; n < 12; ++n) {
        float rn[12];
        #pragma unroll
        for (int m = 0; m < 12; ++m) rn[m] = relS[n][m];
        #pragma unroll
        for (int j = 0; j < 4; ++j) {
            float a = 0.f;
            #pragma unroll
            for (int m = 0; m < 12; ++m) a = fmaf(rn[m], h[m][j], a);
            a2[n][j] = a; s += a; s2 += a * a;
        }
    }
    rs[0][tid] = s; rs[1][tid] = s2;
    __syncthreads();
    for (int o = 128; o > 0; o >>= 1) {
        if (tid < o) { rs[0][tid] += rs[0][tid + o]; rs[1][tid] += rs[1][tid + o]; }
        __syncthreads();
    }
    const float mu = rs[0][0] * (1.f / 12288.f);
    const float var = rs[1][0] * (1.f / 12288.f) - mu * mu;
    const float rstd = rsqrtf(var + LN_EPS);

    #pragma unroll
    for (int n = 0; n < 12; ++n) {
        const float4 wv = *(const float4*)(lnw + (size_t)n * KDIM + c0);
        const float4 bv = *(const float4*)(lnb + (size_t)n * KDIM + c0);
        float4 ov;
        ov.x = fmaxf(fmaf((a2[n][0] - mu) * rstd, wv.x, bv.x), 0.f);
        ov.y = fmaxf(fmaf((a2[n][1] - mu) * rstd, wv.y, bv.y), 0.f);
        ov.z = fmaxf(fmaf((a2[n][2] - mu) * rstd, wv.z, bv.z), 0.f);
        ov.w = fmaxf(fmaf((a2[n][3] - mu) * rstd, wv.w, bv.w), 0.f);
        *(float4*)(out + (size_t)(f * 12 + n) * KDIM + c0) = ov;
    }
}

extern "C" void kernel_launch(void* const* d_in, const int* in_sizes, int n_in,
                              void* d_out, int out_size, void* d_ws, size_t ws_size,
                              hipStream_t stream) {
    const float* x   = (const float*)d_in[0];
    const float* A   = (const float*)d_in[1];
    const float* wth = (const float*)d_in[2];
    const float* bth = (const float*)d_in[3];
    const float* wph = (const float*)d_in[4];
    // const float* bph = (const float*)d_in[5];  // row-bias term cancels in softmax
    const float* wg  = (const float*)d_in[6];
    const float* lnw = (const float*)d_in[7];
    const float* lnb = (const float*)d_in[8];
    float* out = (float*)d_out;

    char* ws = (char*)d_ws;
    const size_t MB = 1ull << 20;
    unsigned short* featB = (unsigned short*)(ws);            // 24 MB
    unsigned short* G     = (unsigned short*)(ws + 24 * MB);  // 24 MB
    unsigned short* H     = (unsigned short*)(ws + 48 * MB);  // 24 MB
    unsigned short* wth_b = (unsigned short*)(ws + 72 * MB);  // 2 MB
    unsigned short* wph_b = (unsigned short*)(ws + 74 * MB);  // 2 MB
    unsigned short* wgT   = (unsigned short*)(ws + 76 * MB);  // 2 MB
    unsigned short* MtB   = (unsigned short*)(ws + 78 * MB);  // 2 MB
    float* vbuf = (float*)(ws + 80 * MB);                     // 4 KB
    float* qbuf = (float*)(ws + 80 * MB + 4096);              // 48 KB

    castw_kernel<<<1024, 256, 0, stream>>>(wth, wph, wth_b, wph_b);
    transwg_kernel<<<dim3(32, 32), 256, 0, stream>>>(wg, wgT);
    feat_kernel<<<BT_TOT, 256, 0, stream>>>(x, featB);
    biasv_kernel<<<4, 256, 0, stream>>>(wph, bth, vbuf);
    qk_kernel<<<48, 256, 0, stream>>>(featB, vbuf, qbuf);
    // Mt[j][i] = sum_o wph[j][o]*wth[i][o]  (= (Wth Wph^T)^T, ready as B^T operand)
    gemm_kernel<false><<<dim3(8, 8, 1), 256, 0, stream>>>(
        wph_b, wth_b, wth_b, nullptr, nullptr, MtB, MtB);
    // G = feat @ M (z=0), H = feat @ Wg (z=1)
    gemm_kernel<false><<<dim3(8, 96, 2), 256, 0, stream>>>(
        featB, MtB, wgT, nullptr, nullptr, G, H);
    relf_kernel<<<BT_TOT, 256, 0, stream>>>(G, featB, H, A, qbuf, lnw, lnb, out);
}

// Round 7
// 234.605 us; speedup vs baseline: 6.5091x; 1.2753x over previous
//
#include <hip/hip_runtime.h>
#include <math.h>
#include <stdint.h>

#define NDIM   12
#define KDIM   1024
#define BT_TOT 1024
#define M_TOT  (BT_TOT * NDIM)       // 12288
#define OUT_MAIN (M_TOT * KDIM)      // 12582912
#define MASK_TH 0.4f                 // 0.005 * 80
#define LN_EPS 1e-5f

typedef float f32x4 __attribute__((ext_vector_type(4)));
typedef short bf16x8 __attribute__((ext_vector_type(8)));
typedef short bf16x4 __attribute__((ext_vector_type(4)));

__device__ __forceinline__ float bf2f(unsigned short u) {
    return __uint_as_float(((unsigned int)u) << 16);
}
__device__ __forceinline__ unsigned short f2bf(float f) {
    unsigned int u = __float_as_uint(f);
    return (unsigned short)((u + 0x7FFFu + ((u >> 16) & 1u)) >> 16);   // RNE
}
__device__ __forceinline__ void gld16(const void* g, void* l) {
    __builtin_amdgcn_global_load_lds(
        (const __attribute__((address_space(1))) unsigned int*)g,
        (__attribute__((address_space(3))) unsigned int*)l, 16, 0, 0);
}

// ---- K0a: wth, wph fp32 -> bf16 (same layout [in][out]) --------------------
__global__ __launch_bounds__(256)
void castw_kernel(const float* __restrict__ wth, const float* __restrict__ wph,
                  unsigned short* __restrict__ t0, unsigned short* __restrict__ t1)
{
    const int bid = blockIdx.x;
    const float* src = bid < 512 ? wth : wph;
    unsigned short* dst = bid < 512 ? t0 : t1;
    const size_t off = (size_t)(bid & 511) * 2048 + (size_t)threadIdx.x * 8;
    const float4 a = *(const float4*)(src + off);
    const float4 b = *(const float4*)(src + off + 4);
    unsigned short o[8] = {f2bf(a.x), f2bf(a.y), f2bf(a.z), f2bf(a.w),
                           f2bf(b.x), f2bf(b.y), f2bf(b.z), f2bf(b.w)};
    *(uint4*)(dst + off) = *(const uint4*)o;
}

// ---- K0b: wg [c][o] fp32 -> wgT [o][c] bf16 --------------------------------
__global__ __launch_bounds__(256)
void transwg_kernel(const float* __restrict__ w, unsigned short* __restrict__ dst)
{
    __shared__ float tile[32][33];
    const int c0 = blockIdx.y * 32, o0 = blockIdx.x * 32;
    const int tx = threadIdx.x & 31, ty = threadIdx.x >> 5;
    #pragma unroll
    for (int i = 0; i < 4; ++i) {
        const int r = ty + i * 8;
        tile[r][tx] = w[(size_t)(c0 + r) * KDIM + o0 + tx];
    }
    __syncthreads();
    #pragma unroll
    for (int i = 0; i < 4; ++i) {
        const int r = ty + i * 8;
        dst[(size_t)(o0 + r) * KDIM + c0 + tx] = f2bf(tile[tx][r]);
    }
}

// ---- K1: x [B,C,T,N] -> featB [B*768][1024] bf16 via coalesced transpose ---
// per b: source plane [c=1024][p=t*12+n=768]; dest rows b*768+p, col c.
__global__ __launch_bounds__(256)
void featT_kernel(const float* __restrict__ x, unsigned short* __restrict__ featB)
{
    const int b = blockIdx.z;
    const int c0 = blockIdx.y * 32;     // 32 tiles
    const int p0 = blockIdx.x * 32;     // 24 tiles
    __shared__ float tile[32][33];
    const int tx = threadIdx.x & 31, ty = threadIdx.x >> 5;
    const float* src = x + (size_t)b * KDIM * 768;
    #pragma unroll
    for (int i = 0; i < 4; ++i) {
        const int cc = ty + i * 8;
        tile[cc][tx] = src[(size_t)(c0 + cc) * 768 + p0 + tx];
    }
    __syncthreads();
    unsigned short* dst = featB + (size_t)b * 768 * KDIM;
    #pragma unroll
    for (int i = 0; i < 4; ++i) {
        const int pp = ty + i * 8;
        dst[(size_t)(p0 + pp) * KDIM + c0 + tx] = f2bf(tile[tx][pp]);
    }
}

// ---- K2: v = wph @ b_theta (wave per row) ----------------------------------
__global__ __launch_bounds__(256)
void biasv_kernel(const float* __restrict__ wph, const float* __restrict__ btheta,
                  float* __restrict__ v)
{
    const int lane = threadIdx.x & 63, w = threadIdx.x >> 6;
    const int j = blockIdx.x * 4 + w;              // grid 256 -> 1024 rows
    const float4* row = (const float4*)(wph + (size_t)j * KDIM);
    const float4* bt4 = (const float4*)btheta;
    float s = 0.f;
    #pragma unroll
    for (int i = 0; i < 4; ++i) {
        const float4 a = row[lane + i * 64], b = bt4[lane + i * 64];
        s += a.x * b.x + a.y * b.y + a.z * b.z + a.w * b.w;
    }
    #pragma unroll
    for (int msk = 32; msk >= 1; msk >>= 1) s += __shfl_xor(s, msk, 64);
    if (lane == 0) v[j] = s;
}

// ---- K3: q[r] = featB[r] . v  (wave per row, coalesced) --------------------
__global__ __launch_bounds__(256)
void qk_kernel(const unsigned short* __restrict__ featB, const float* __restrict__ v,
               float* __restrict__ q)
{
    __shared__ float vS[KDIM];
    const int tid = threadIdx.x, lane = tid & 63, w = tid >> 6;
    #pragma unroll
    for (int i = 0; i < 4; ++i) vS[tid + i * 256] = v[tid + i * 256];
    __syncthreads();
    const int r = blockIdx.x * 4 + w;              // grid 3072 -> 12288 rows
    const unsigned short* row = featB + (size_t)r * KDIM;
    float s = 0.f;
    #pragma unroll
    for (int h = 0; h < 2; ++h) {
        const int e0 = h * 512 + lane * 8;
        const bf16x8 a = *(const bf16x8*)&row[e0];
        #pragma unroll
        for (int j = 0; j < 8; ++j)
            s = fmaf(bf2f((unsigned short)a[j]), vS[e0 + j], s);
    }
    #pragma unroll
    for (int msk = 32; msk >= 1; msk >>= 1) s += __shfl_xor(s, msk, 64);
    if (lane == 0) q[r] = s;
}

// ---- K4/K5: C[M,1024] = A[M,1024] @ B^T, bf16 MFMA -------------------------
// SWZ: 1D grid 1536; bid&7 = XCD (round-robin dispatch); s=bid>>3 sweeps n
// fastest so each XCD reuses one A-panel from its own L2 (fixes 8x over-fetch).
template<bool SWZ>
__global__ __launch_bounds__(256)
void gemm_kernel(const unsigned short* __restrict__ A,
                 const unsigned short* __restrict__ B0, const unsigned short* __restrict__ B1,
                 unsigned short* __restrict__ C0, unsigned short* __restrict__ C1)
{
    int m0, n0, zz;
    if (SWZ) {
        const int bid = blockIdx.x;
        const int c = bid & 7, s = bid >> 3;
        const int n = s & 7, mm = (s >> 3) % 12, z = s / 96;
        m0 = (c * 12 + mm) * 128; n0 = n * 128; zz = z;
    } else {
        m0 = blockIdx.y * 128; n0 = blockIdx.x * 128; zz = blockIdx.z;
    }
    const unsigned short* B = zz ? B1 : B0;
    unsigned short* C       = zz ? C1 : C0;

    const int tid = threadIdx.x, lane = tid & 63, wid = tid >> 6;
    const int wr = wid >> 1, wc = wid & 1;

    __shared__ __align__(16) unsigned short As[128 * 32];
    __shared__ __align__(16) unsigned short Bs[128 * 32];

    f32x4 acc[4][4] = {};

    const int srow = tid >> 2;
    const int scol = (tid & 3) * 16;

    for (int k0 = 0; k0 < KDIM; k0 += 32) {
        const char* gA = (const char*)A + ((size_t)(m0 + srow) * KDIM + k0) * 2 + scol;
        const char* gB = (const char*)B + ((size_t)(n0 + srow) * KDIM + k0) * 2 + scol;
        char* lA = (char*)As + wid * 1024;
        char* lB = (char*)Bs + wid * 1024;
        gld16(gA, lA);
        gld16(gA + (size_t)64 * KDIM * 2, lA + 4096);
        gld16(gB, lB);
        gld16(gB + (size_t)64 * KDIM * 2, lB + 4096);
        __syncthreads();

        bf16x8 af[4], bfr[4];
        const int rA = wr * 64 + (lane & 15);
        const int rB = wc * 64 + (lane & 15);
        const int kq = (lane >> 4) * 8;
        #pragma unroll
        for (int mi = 0; mi < 4; ++mi)
            af[mi] = *(const bf16x8*)&As[(rA + mi * 16) * 32 + kq];
        #pragma unroll
        for (int ni = 0; ni < 4; ++ni)
            bfr[ni] = *(const bf16x8*)&Bs[(rB + ni * 16) * 32 + kq];
        #pragma unroll
        for (int mi = 0; mi < 4; ++mi)
            #pragma unroll
            for (int ni = 0; ni < 4; ++ni)
                acc[mi][ni] = __builtin_amdgcn_mfma_f32_16x16x32_bf16(
                    af[mi], bfr[ni], acc[mi][ni], 0, 0, 0);
        __syncthreads();
    }

    // C/D layout: col=lane&15, row=(lane>>4)*4+reg  [m89/m91]
    #pragma unroll
    for (int mi = 0; mi < 4; ++mi) {
        const int gr0 = m0 + wr * 64 + mi * 16 + (lane >> 4) * 4;
        #pragma unroll
        for (int ni = 0; ni < 4; ++ni) {
            const int gc = n0 + wc * 64 + ni * 16 + (lane & 15);
            const f32x4 v = acc[mi][ni];
            #pragma unroll
            for (int reg = 0; reg < 4; ++reg)
                C[(size_t)(gr0 + reg) * KDIM + gc] = f2bf(v[reg]);
        }
    }
}

// ---- K6: fused logits(MFMA) + mask/softmax + agg2 = rel@H + LN + ReLU ------
__global__ __launch_bounds__(256)
void relf_kernel(const unsigned short* __restrict__ G,
                 const unsigned short* __restrict__ featB,
                 const unsigned short* __restrict__ H,
                 const float* __restrict__ Abox, const float* __restrict__ q,
                 const float* __restrict__ lnw, const float* __restrict__ lnb,
                 float* __restrict__ out)
{
    const int f = blockIdx.x, tid = threadIdx.x, lane = tid & 63, w = tid >> 6;
    __shared__ float Lred[4][16][16];
    __shared__ float relS[12][12];
    __shared__ float cxS[12], cyS[12], sqS[12], qS[12];
    __shared__ float rs[2][256];

    if (tid < 12) {
        const float4 box = *(const float4*)(Abox + ((size_t)f * 12 + tid) * 4);
        const float cx = (box.x + box.z) * 0.5f, cy = (box.y + box.w) * 0.5f;
        cxS[tid] = cx; cyS[tid] = cy; sqS[tid] = cx * cx + cy * cy;
        qS[tid] = q[f * 12 + tid];
    }

    // logits = G . feat^T via MFMA; pad rows 12..15 with row 0 (their output
    // rows/cols are discarded)
    const int r = lane & 15, rr = r < 12 ? r : 0;
    const int kq = (lane >> 4) * 8;
    const unsigned short* gG = G + (size_t)(f * 12 + rr) * KDIM;
    const unsigned short* gF = featB + (size_t)(f * 12 + rr) * KDIM;
    f32x4 acc = {};
    #pragma unroll
    for (int s8 = 0; s8 < 8; ++s8) {
        const int k0 = (w * 8 + s8) * 32 + kq;
        const bf16x8 a = *(const bf16x8*)(gG + k0);
        const bf16x8 b = *(const bf16x8*)(gF + k0);
        acc = __builtin_amdgcn_mfma_f32_16x16x32_bf16(a, b, acc, 0, 0, 0);
    }
    {
        const int row0 = (lane >> 4) * 4, col = lane & 15;
        #pragma unroll
        for (int reg = 0; reg < 4; ++reg) Lred[w][row0 + reg][col] = acc[reg];
    }
    __syncthreads();

    if (tid < 12) {
        const int n = tid;
        float l[12], mx = -3.4e38f;
        #pragma unroll
        for (int m = 0; m < 12; ++m) {
            const float L = Lred[0][n][m] + Lred[1][n][m] + Lred[2][n][m] + Lred[3][n][m];
            float val = (L + qS[m]) * 0.03125f;    // 1/sqrt(1024); row/const bias cancel
            const float d2 = sqS[n] - 2.f * (cxS[n] * cxS[m] + cyS[n] * cyS[m]) + sqS[m];
            const float dist = sqrtf(fmaxf(d2, 0.f));
            if (dist > MASK_TH) val = -INFINITY;
            l[m] = val; mx = fmaxf(mx, val);
        }
        float s = 0.f, e[12];
        #pragma unroll
        for (int m = 0; m < 12; ++m) { e[m] = expf(l[m] - mx); s += e[m]; }
        const float inv = 1.f / s;
        float* orel = out + (size_t)OUT_MAIN + (size_t)f * 144 + n * 12;
        #pragma unroll
        for (int m = 0; m < 12; ++m) {
            const float rv = e[m] * inv;
            relS[n][m] = rv;
            orel[m] = rv;
        }
    }
    __syncthreads();

    // agg2[n][c] = sum_m rel[n][m] * H[m][c];  thread owns c = tid*4 .. tid*4+3
    const int c0 = tid * 4;
    float h[12][4];
    #pragma unroll
    for (int m = 0; m < 12; ++m) {
        const bf16x4 h4 = *(const bf16x4*)(H + (size_t)(f * 12 + m) * KDIM + c0);
        #pragma unroll
        for (int j = 0; j < 4; ++j) h[m][j] = bf2f((unsigned short)h4[j]);
    }
    float a2[12][4];
    float s = 0.f, s2 = 0.f;
    #pragma unroll
    for (int n = 0; n < 12; ++n) {
        float rn[12];
        #pragma unroll
        for (int m = 0; m < 12; ++m) rn[m] = relS[n][m];
        #pragma unroll
        for (int j = 0; j < 4; ++j) {
            float a = 0.f;
            #pragma unroll
            for (int m = 0; m < 12; ++m) a = fmaf(rn[m], h[m][j], a);
            a2[n][j] = a; s += a; s2 += a * a;
        }
    }
    rs[0][tid] = s; rs[1][tid] = s2;
    __syncthreads();
    for (int o = 128; o > 0; o >>= 1) {
        if (tid < o) { rs[0][tid] += rs[0][tid + o]; rs[1][tid] += rs[1][tid + o]; }
        __syncthreads();
    }
    const float mu = rs[0][0] * (1.f / 12288.f);
    const float var = rs[1][0] * (1.f / 12288.f) - mu * mu;
    const float rstd = rsqrtf(var + LN_EPS);

    #pragma unroll
    for (int n = 0; n < 12; ++n) {
        const float4 wv = *(const float4*)(lnw + (size_t)n * KDIM + c0);
        const float4 bv = *(const float4*)(lnb + (size_t)n * KDIM + c0);
        float4 ov;
        ov.x = fmaxf(fmaf((a2[n][0] - mu) * rstd, wv.x, bv.x), 0.f);
        ov.y = fmaxf(fmaf((a2[n][1] - mu) * rstd, wv.y, bv.y), 0.f);
        ov.z = fmaxf(fmaf((a2[n][2] - mu) * rstd, wv.z, bv.z), 0.f);
        ov.w = fmaxf(fmaf((a2[n][3] - mu) * rstd, wv.w, bv.w), 0.f);
        *(float4*)(out + (size_t)(f * 12 + n) * KDIM + c0) = ov;
    }
}

extern "C" void kernel_launch(void* const* d_in, const int* in_sizes, int n_in,
                              void* d_out, int out_size, void* d_ws, size_t ws_size,
                              hipStream_t stream) {
    const float* x   = (const float*)d_in[0];
    const float* A   = (const float*)d_in[1];
    const float* wth = (const float*)d_in[2];
    const float* bth = (const float*)d_in[3];
    const float* wph = (const float*)d_in[4];
    // bph: row-bias term cancels in softmax
    const float* wg  = (const float*)d_in[6];
    const float* lnw = (const float*)d_in[7];
    const float* lnb = (const float*)d_in[8];
    float* out = (float*)d_out;

    char* ws = (char*)d_ws;
    const size_t MB = 1ull << 20;
    unsigned short* featB = (unsigned short*)(ws);            // 24 MB
    unsigned short* G     = (unsigned short*)(ws + 24 * MB);  // 24 MB
    unsigned short* H     = (unsigned short*)(ws + 48 * MB);  // 24 MB
    unsigned short* wth_b = (unsigned short*)(ws + 72 * MB);  // 2 MB
    unsigned short* wph_b = (unsigned short*)(ws + 74 * MB);  // 2 MB
    unsigned short* wgT   = (unsigned short*)(ws + 76 * MB);  // 2 MB
    unsigned short* MtB   = (unsigned short*)(ws + 78 * MB);  // 2 MB
    float* vbuf = (float*)(ws + 80 * MB);                     // 4 KB
    float* qbuf = (float*)(ws + 80 * MB + 4096);              // 48 KB

    castw_kernel<<<1024, 256, 0, stream>>>(wth, wph, wth_b, wph_b);
    transwg_kernel<<<dim3(32, 32), 256, 0, stream>>>(wg, wgT);
    featT_kernel<<<dim3(24, 32, 16), 256, 0, stream>>>(x, featB);
    biasv_kernel<<<256, 256, 0, stream>>>(wph, bth, vbuf);
    qk_kernel<<<3072, 256, 0, stream>>>(featB, vbuf, qbuf);
    // Mt[j][i] = sum_o wph[j][o]*wth[i][o]  (ready as B^T operand)
    gemm_kernel<false><<<dim3(8, 8, 1), 256, 0, stream>>>(
        wph_b, wth_b, wth_b, MtB, MtB);
    // G = feat @ M (z=0), H = feat @ Wg (z=1); XCD-swizzled 1D grid
    gemm_kernel<true><<<1536, 256, 0, stream>>>(
        featB, MtB, wgT, G, H);
    relf_kernel<<<BT_TOT, 256, 0, stream>>>(G, featB, H, A, qbuf, lnw, lnb, out);
}

// Round 8
// 220.619 us; speedup vs baseline: 6.9218x; 1.0634x over previous
//
#include <hip/hip_runtime.h>
#include <math.h>
#include <stdint.h>

#define NDIM   12
#define KDIM   1024
#define BT_TOT 1024
#define M_TOT  (BT_TOT * NDIM)       // 12288
#define OUT_MAIN (M_TOT * KDIM)      // 12582912
#define MASK_TH 0.4f                 // 0.005 * 80
#define LN_EPS 1e-5f

typedef float f32x4 __attribute__((ext_vector_type(4)));
typedef short bf16x8 __attribute__((ext_vector_type(8)));
typedef short bf16x4 __attribute__((ext_vector_type(4)));

__device__ __forceinline__ float bf2f(unsigned short u) {
    return __uint_as_float(((unsigned int)u) << 16);
}
__device__ __forceinline__ unsigned short f2bf(float f) {
    unsigned int u = __float_as_uint(f);
    return (unsigned short)((u + 0x7FFFu + ((u >> 16) & 1u)) >> 16);   // RNE
}
__device__ __forceinline__ void gld16(const void* g, void* l) {
    __builtin_amdgcn_global_load_lds(
        (const __attribute__((address_space(1))) unsigned int*)g,
        (__attribute__((address_space(3))) unsigned int*)l, 16, 0, 0);
}

// ---- K0: ALL preprocessing in one launch -----------------------------------
// bid [0,1024): cast wth/wph fp32->bf16
// bid [1024,2048): transpose wg -> wgT [o][c] bf16
// bid [2048,2304): vbuf = wph @ b_theta (wave per row)
// bid [2304,8448): x [B,C,T,N] -> featB [B*768][1024] bf16 (64c x 32p tiles)
__global__ __launch_bounds__(256)
void prep_kernel(const float* __restrict__ x,   const float* __restrict__ wth,
                 const float* __restrict__ wph, const float* __restrict__ bth,
                 const float* __restrict__ wg,
                 unsigned short* __restrict__ wth_b, unsigned short* __restrict__ wph_b,
                 unsigned short* __restrict__ wgT,   float* __restrict__ vbuf,
                 unsigned short* __restrict__ featB)
{
    const int bid = blockIdx.x, tid = threadIdx.x;
    __shared__ float tileF[64][33];

    if (bid < 1024) {                       // cast weights to bf16
        const float* src = bid < 512 ? wth : wph;
        unsigned short* dst = bid < 512 ? wth_b : wph_b;
        const size_t off = (size_t)(bid & 511) * 2048 + (size_t)tid * 8;
        const float4 a = *(const float4*)(src + off);
        const float4 b = *(const float4*)(src + off + 4);
        unsigned short o[8] = {f2bf(a.x), f2bf(a.y), f2bf(a.z), f2bf(a.w),
                               f2bf(b.x), f2bf(b.y), f2bf(b.z), f2bf(b.w)};
        *(uint4*)(dst + off) = *(const uint4*)o;
    } else if (bid < 2048) {                // transpose wg
        const int b2 = bid - 1024;
        const int o0 = (b2 & 31) * 32, c0 = (b2 >> 5) * 32;
        const int tx = tid & 31, ty = tid >> 5;
        #pragma unroll
        for (int i = 0; i < 4; ++i) {
            const int r = ty + i * 8;
            tileF[r][tx] = wg[(size_t)(c0 + r) * KDIM + o0 + tx];
        }
        __syncthreads();
        #pragma unroll
        for (int i = 0; i < 4; ++i) {
            const int r = ty + i * 8;
            wgT[(size_t)(o0 + r) * KDIM + c0 + tx] = f2bf(tileF[tx][r]);
        }
    } else if (bid < 2304) {                // vbuf = wph @ b_theta
        const int b3 = bid - 2048;
        const int lane = tid & 63, w = tid >> 6;
        const int j = b3 * 4 + w;
        const float4* row = (const float4*)(wph + (size_t)j * KDIM);
        const float4* bt4 = (const float4*)bth;
        float s = 0.f;
        #pragma unroll
        for (int i = 0; i < 4; ++i) {
            const float4 a = row[lane + i * 64], b = bt4[lane + i * 64];
            s += a.x * b.x + a.y * b.y + a.z * b.z + a.w * b.w;
        }
        #pragma unroll
        for (int msk = 32; msk >= 1; msk >>= 1) s += __shfl_xor(s, msk, 64);
        if (lane == 0) vbuf[j] = s;
    } else {                                // feat transpose, 64c x 32p tiles
        const int b4 = bid - 2304;
        const int px = b4 % 24;
        const int rest = b4 / 24;
        const int cx = rest & 15, b = rest >> 4;
        const int p0 = px * 32, c0 = cx * 64;
        const float* src = x + (size_t)b * KDIM * 768;
        #pragma unroll
        for (int i = 0; i < 8; ++i) {
            const int cl = (tid >> 5) + i * 8;
            tileF[cl][tid & 31] = src[(size_t)(c0 + cl) * 768 + p0 + (tid & 31)];
        }
        __syncthreads();
        unsigned short* dst = featB + ((size_t)b * 768 + p0) * KDIM;
        #pragma unroll
        for (int i = 0; i < 8; ++i) {
            const int pp = (tid >> 6) + i * 4;
            const int cl = tid & 63;
            dst[(size_t)pp * KDIM + c0 + cl] = f2bf(tileF[cl][pp]);
        }
    }
}

// ---- K1/K2: C[M,1024] = A[M,1024] @ B^T, bf16 MFMA, BK=64, swizzled LDS ----
// Staging (rule #21): linear LDS dest (gload_lds scatters lane*16), source
// chunk pre-swizzled ^ (row&7); ds_read applies the same XOR -> 2-way max.
// SWZ grid 1536: bid&7 = XCD slice, n fastest -> A-panel L2 reuse per XCD.
template<bool SWZ>
__global__ __launch_bounds__(256)
void gemm_kernel(const unsigned short* __restrict__ A,
                 const unsigned short* __restrict__ B0, const unsigned short* __restrict__ B1,
                 unsigned short* __restrict__ C0, unsigned short* __restrict__ C1)
{
    int m0, n0, zz;
    if (SWZ) {
        const int bid = blockIdx.x;
        const int c = bid & 7, s = bid >> 3;
        const int n = s & 7, mm = (s >> 3) % 12, z = s / 96;
        m0 = (c * 12 + mm) * 128; n0 = n * 128; zz = z;
    } else {
        m0 = blockIdx.y * 128; n0 = blockIdx.x * 128; zz = blockIdx.z;
    }
    const unsigned short* B = zz ? B1 : B0;
    unsigned short* C       = zz ? C1 : C0;

    const int tid = threadIdx.x, lane = tid & 63, wid = tid >> 6;
    const int wr = wid >> 1, wc = wid & 1;

    __shared__ __align__(16) unsigned short As[128 * 64];   // 16 KB
    __shared__ __align__(16) unsigned short Bs[128 * 64];   // 16 KB

    f32x4 acc[4][4] = {};

    const int srow_w = wid * 8 + (lane >> 3);   // + i*32
    const int schunk = lane & 7;

    for (int k0 = 0; k0 < KDIM; k0 += 64) {
        #pragma unroll
        for (int i = 0; i < 4; ++i) {
            const int row = srow_w + i * 32;
            const int gchunk = schunk ^ (row & 7);
            const char* srcA = (const char*)A + ((size_t)(m0 + row) * KDIM + k0) * 2 + gchunk * 16;
            const char* srcB = (const char*)B + ((size_t)(n0 + row) * KDIM + k0) * 2 + gchunk * 16;
            char* la = (char*)As + i * 4096 + wid * 1024;
            char* lb = (char*)Bs + i * 4096 + wid * 1024;
            gld16(srcA, la);
            gld16(srcB, lb);
        }
        __syncthreads();

        #pragma unroll
        for (int ks = 0; ks < 2; ++ks) {
            bf16x8 af[4], bfr[4];
            const int cch = ks * 4 + (lane >> 4);
            #pragma unroll
            for (int mi = 0; mi < 4; ++mi) {
                const int r = wr * 64 + (lane & 15) + mi * 16;
                af[mi] = *(const bf16x8*)((const char*)As + r * 128 + ((cch ^ (r & 7)) * 16));
            }
            #pragma unroll
            for (int ni = 0; ni < 4; ++ni) {
                const int r = wc * 64 + (lane & 15) + ni * 16;
                bfr[ni] = *(const bf16x8*)((const char*)Bs + r * 128 + ((cch ^ (r & 7)) * 16));
            }
            #pragma unroll
            for (int mi = 0; mi < 4; ++mi)
                #pragma unroll
                for (int ni = 0; ni < 4; ++ni)
                    acc[mi][ni] = __builtin_amdgcn_mfma_f32_16x16x32_bf16(
                        af[mi], bfr[ni], acc[mi][ni], 0, 0, 0);
        }
        __syncthreads();
    }

    // C/D layout: col=lane&15, row=(lane>>4)*4+reg  [m89/m91]
    #pragma unroll
    for (int mi = 0; mi < 4; ++mi) {
        const int gr0 = m0 + wr * 64 + mi * 16 + (lane >> 4) * 4;
        #pragma unroll
        for (int ni = 0; ni < 4; ++ni) {
            const int gc = n0 + wc * 64 + ni * 16 + (lane & 15);
            const f32x4 v = acc[mi][ni];
            #pragma unroll
            for (int reg = 0; reg < 4; ++reg)
                C[(size_t)(gr0 + reg) * KDIM + gc] = f2bf(v[reg]);
        }
    }
}

// ---- K3: fused logits(MFMA) + q + mask/softmax + agg2 = rel@H + LN + ReLU --
__global__ __launch_bounds__(256)
void relf_kernel(const unsigned short* __restrict__ G,
                 const unsigned short* __restrict__ featB,
                 const unsigned short* __restrict__ H,
                 const float* __restrict__ Abox, const float* __restrict__ vbuf,
                 const float* __restrict__ lnw, const float* __restrict__ lnb,
                 float* __restrict__ out)
{
    const int f = blockIdx.x, tid = threadIdx.x, lane = tid & 63, w = tid >> 6;
    __shared__ float Lred[4][16][16];
    __shared__ float relS[12][12];
    __shared__ float cxS[12], cyS[12], sqS[12];
    __shared__ float qred[4][12];
    __shared__ float rs[2][256];

    if (tid < 12) {
        const float4 box = *(const float4*)(Abox + ((size_t)f * 12 + tid) * 4);
        const float cx = (box.x + box.z) * 0.5f, cy = (box.y + box.w) * 0.5f;
        cxS[tid] = cx; cyS[tid] = cy; sqS[tid] = cx * cx + cy * cy;
    }

    // logits = G . feat^T via MFMA; pad rows 12..15 with row 0 (discarded)
    const int r = lane & 15, rr = r < 12 ? r : 0;
    const int kq = (lane >> 4) * 8;
    const unsigned short* gG = G + (size_t)(f * 12 + rr) * KDIM;
    const unsigned short* gF = featB + (size_t)(f * 12 + rr) * KDIM;
    f32x4 acc = {};
    #pragma unroll
    for (int s8 = 0; s8 < 8; ++s8) {
        const int k0 = (w * 8 + s8) * 32 + kq;
        const bf16x8 a = *(const bf16x8*)(gG + k0);
        const bf16x8 b = *(const bf16x8*)(gF + k0);
        acc = __builtin_amdgcn_mfma_f32_16x16x32_bf16(a, b, acc, 0, 0, 0);
    }
    {
        const int row0 = (lane >> 4) * 4, col = lane & 15;
        #pragma unroll
        for (int reg = 0; reg < 4; ++reg) Lred[w][row0 + reg][col] = acc[reg];
    }

    // q[m] = feat[m] . v  (column-bias term); per-thread 4-col partials
    const int c0 = tid * 4;
    {
        const float4 v4 = *(const float4*)(vbuf + c0);
        float qp[12];
        #pragma unroll
        for (int m = 0; m < 12; ++m) {
            const bf16x4 fm = *(const bf16x4*)(featB + (size_t)(f * 12 + m) * KDIM + c0);
            qp[m] = bf2f((unsigned short)fm[0]) * v4.x + bf2f((unsigned short)fm[1]) * v4.y
                  + bf2f((unsigned short)fm[2]) * v4.z + bf2f((unsigned short)fm[3]) * v4.w;
        }
        #pragma unroll
        for (int msk = 32; msk >= 1; msk >>= 1)
            #pragma unroll
            for (int m = 0; m < 12; ++m) qp[m] += __shfl_xor(qp[m], msk, 64);
        if (lane == 0) {
            #pragma unroll
            for (int m = 0; m < 12; ++m) qred[w][m] = qp[m];
        }
    }
    __syncthreads();

    if (tid < 12) {
        const int n = tid;
        float l[12], mx = -3.4e38f;
        #pragma unroll
        for (int m = 0; m < 12; ++m) {
            const float L = Lred[0][n][m] + Lred[1][n][m] + Lred[2][n][m] + Lred[3][n][m];
            const float qm = qred[0][m] + qred[1][m] + qred[2][m] + qred[3][m];
            float val = (L + qm) * 0.03125f;     // 1/sqrt(1024); row/const bias cancel
            const float d2 = sqS[n] - 2.f * (cxS[n] * cxS[m] + cyS[n] * cyS[m]) + sqS[m];
            const float dist = sqrtf(fmaxf(d2, 0.f));
            if (dist > MASK_TH) val = -INFINITY;
            l[m] = val; mx = fmaxf(mx, val);
        }
        float s = 0.f, e[12];
        #pragma unroll
        for (int m = 0; m < 12; ++m) { e[m] = expf(l[m] - mx); s += e[m]; }
        const float inv = 1.f / s;
        float* orel = out + (size_t)OUT_MAIN + (size_t)f * 144 + n * 12;
        #pragma unroll
        for (int m = 0; m < 12; ++m) {
            const float rv = e[m] * inv;
            relS[n][m] = rv;
            orel[m] = rv;
        }
    }
    __syncthreads();

    // agg2[n][c] = sum_m rel[n][m] * H[m][c];  thread owns c = tid*4 .. tid*4+3
    float h[12][4];
    #pragma unroll
    for (int m = 0; m < 12; ++m) {
        const bf16x4 h4 = *(const bf16x4*)(H + (size_t)(f * 12 + m) * KDIM + c0);
        #pragma unroll
        for (int j = 0; j < 4; ++j) h[m][j] = bf2f((unsigned short)h4[j]);
    }
    float a2[12][4];
    float s = 0.f, s2 = 0.f;
    #pragma unroll
    for (int n = 0; n < 12; ++n) {
        float rn[12];
        #pragma unroll
        for (int m = 0; m < 12; ++m) rn[m] = relS[n][m];
        #pragma unroll
        for (int j = 0; j < 4; ++j) {
            float a = 0.f;
            #pragma unroll
            for (int m = 0; m < 12; ++m) a = fmaf(rn[m], h[m][j], a);
            a2[n][j] = a; s += a; s2 += a * a;
        }
    }
    rs[0][tid] = s; rs[1][tid] = s2;
    __syncthreads();
    for (int o = 128; o > 0; o >>= 1) {
        if (tid < o) { rs[0][tid] += rs[0][tid + o]; rs[1][tid] += rs[1][tid + o]; }
        __syncthreads();
    }
    const float mu = rs[0][0] * (1.f / 12288.f);
    const float var = rs[1][0] * (1.f / 12288.f) - mu * mu;
    const float rstd = rsqrtf(var + LN_EPS);

    #pragma unroll
    for (int n = 0; n < 12; ++n) {
        const float4 wv = *(const float4*)(lnw + (size_t)n * KDIM + c0);
        const float4 bv = *(const float4*)(lnb + (size_t)n * KDIM + c0);
        float4 ov;
        ov.x = fmaxf(fmaf((a2[n][0] - mu) * rstd, wv.x, bv.x), 0.f);
        ov.y = fmaxf(fmaf((a2[n][1] - mu) * rstd, wv.y, bv.y), 0.f);
        ov.z = fmaxf(fmaf((a2[n][2] - mu) * rstd, wv.z, bv.z), 0.f);
        ov.w = fmaxf(fmaf((a2[n][3] - mu) * rstd, wv.w, bv.w), 0.f);
        *(float4*)(out + (size_t)(f * 12 + n) * KDIM + c0) = ov;
    }
}

extern "C" void kernel_launch(void* const* d_in, const int* in_sizes, int n_in,
                              void* d_out, int out_size, void* d_ws, size_t ws_size,
                              hipStream_t stream) {
    const float* x   = (const float*)d_in[0];
    const float* A   = (const float*)d_in[1];
    const float* wth = (const float*)d_in[2];
    const float* bth = (const float*)d_in[3];
    const float* wph = (const float*)d_in[4];
    // bph: row-bias term cancels in softmax
    const float* wg  = (const float*)d_in[6];
    const float* lnw = (const float*)d_in[7];
    const float* lnb = (const float*)d_in[8];
    float* out = (float*)d_out;

    char* ws = (char*)d_ws;
    const size_t MB = 1ull << 20;
    unsigned short* featB = (unsigned short*)(ws);            // 24 MB
    unsigned short* G     = (unsigned short*)(ws + 24 * MB);  // 24 MB
    unsigned short* H     = (unsigned short*)(ws + 48 * MB);  // 24 MB
    unsigned short* wth_b = (unsigned short*)(ws + 72 * MB);  // 2 MB
    unsigned short* wph_b = (unsigned short*)(ws + 74 * MB);  // 2 MB
    unsigned short* wgT   = (unsigned short*)(ws + 76 * MB);  // 2 MB
    unsigned short* MtB   = (unsigned short*)(ws + 78 * MB);  // 2 MB
    float* vbuf = (float*)(ws + 80 * MB);                     // 4 KB

    prep_kernel<<<8448, 256, 0, stream>>>(x, wth, wph, bth, wg,
                                          wth_b, wph_b, wgT, vbuf, featB);
    // Mt[j][i] = sum_o wph[j][o]*wth[i][o]  (ready as B^T operand)
    gemm_kernel<false><<<dim3(8, 8, 1), 256, 0, stream>>>(
        wph_b, wth_b, wth_b, MtB, MtB);
    // G = feat @ M (z=0), H = feat @ Wg (z=1); XCD-swizzled 1D grid
    gemm_kernel<true><<<1536, 256, 0, stream>>>(
        featB, MtB, wgT, G, H);
    relf_kernel<<<BT_TOT, 256, 0, stream>>>(G, featB, H, A, vbuf, lnw, lnb, out);
}